// Round 7
// baseline (217.125 us; speedup 1.0000x reference)
//
#include <hip/hip_runtime.h>
#include <math.h>

// CTC forward (keras ctc_batch_cost), B=1024 T=256 C=128 L=64, S=129.
// R7: producer/consumer block. 256 threads = 4 waves per batch element:
//   wave 0  : consumer -- runs the serial prob-domain recurrence from LDS.
//   waves1-3: loaders  -- stream y_pred chunks (8 rows = 4KB) round-robin,
//             depth-2 register ping-pong each (6 chunks in flight/block),
//             ds_write_b128 into an 8-slot LDS ring, publish LDS flag per
//             chunk (data ordered before flag via lgkmcnt(0)).
// No s_barrier after init => no full vmcnt(0) barrier drain; loader waits
// are compiler-emitted per-wave vmcnt(4) on the VGPR ping-pong. 4 blocks/CU
// x 4 waves = 16 waves/CU; ~24 MB chip-wide loads in flight.
// Recurrence (validated absmax 0 in R2-R5): probability-domain semiring,
// q=(p+eps)*128, lane i owns states 2i/2i+1, one DPP wave_shr per step,
// wave-uniform renorm every 8 steps with exponent accumulator.

#define Bn 1024
#define Tn 256
#define Cn 128
#define Ln 64
#define BLANK 127
#define U 8
#define NCH (Tn / U)      // 32 chunks
#define RING 8            // 8 x 4KB = 32 KB ring
#define EPS128 (1e-7f * 128.0f)
#define LN2 0.69314718055994530942f

#define WAIT_LGKM0() __builtin_amdgcn_s_waitcnt(0xC07F)   // lgkmcnt(0) only

template <int CTRL>
__device__ __forceinline__ float dpp_movf(float x) {
    return __int_as_float(__builtin_amdgcn_update_dpp(
        0, __float_as_int(x), CTRL, 0xF, 0xF, true));
}
__device__ __forceinline__ int dpp_shr1_i(int x) {
    return __builtin_amdgcn_update_dpp(0, x, 0x138, 0xF, 0xF, true);
}

__global__ __launch_bounds__(256)
void ctc_pc_kernel(const int* __restrict__ yt,
                   const float* __restrict__ yp,
                   float* __restrict__ out) {
    __shared__ __align__(16) float ring[RING][U * Cn];   // 32 KB
    __shared__ int flags[NCH];
    __shared__ int cons_prog;
    volatile int* vfl = flags;
    volatile int* vpr = &cons_prog;

    const int b = blockIdx.x;
    const int t = threadIdx.x;
    const int w = t >> 6;     // wave 0..3
    const int i = t & 63;

    if (t < NCH) flags[t] = 0;
    if (t == 0)  cons_prog = 0;
    __syncthreads();          // once, before any data movement

    const float* gb = yp + (size_t)b * (Tn * Cn);

    if (w != 0) {
        // ---------------- loader wave ----------------
        const int start = w - 1;              // chunks start, start+3, ...
        float4 fA[4], fB[4];
        auto issue = [&](int c, float4* f) {
            const float4* p = (const float4*)(gb + c * (U * Cn)) + i;
#pragma unroll
            for (int k = 0; k < 4; ++k) f[k] = p[k * 64];
        };
        auto put = [&](int c, const float4* f) {
            while (*vpr < c - (RING - 1)) __builtin_amdgcn_s_sleep(1);
            float4* d = (float4*)ring[c & (RING - 1)] + i;
#pragma unroll
            for (int k = 0; k < 4; ++k) d[k * 64] = f[k];   // waits vmcnt(own)
            WAIT_LGKM0();                  // data in LDS before flag
            if (i == 0) vfl[c] = 1;
        };
        issue(start, fA);
        if (start + 3 < NCH) issue(start + 3, fB);
        for (int c = start; c < NCH; c += 6) {
            put(c, fA);
            if (c + 6 < NCH) issue(c + 6, fA);
            if (c + 3 < NCH) {
                put(c + 3, fB);
                if (c + 9 < NCH) issue(c + 9, fB);
            }
        }
        return;
    }

    // ---------------- consumer wave (wave 0) ----------------
    const int li = yt[b * Ln + i];
    const int ll = dpp_shr1_i(li);
    const float skf = (li != ll) ? 1.0f : 0.0f;

    float qlA[U], qbA[U], qlB[U], qbB[U];
    auto spinflag = [&](int c) {
        while (vfl[c] == 0) __builtin_amdgcn_s_sleep(1);
        __builtin_amdgcn_sched_barrier(0);
    };
    auto qread = [&](int c, float* ql, float* qb) {
        const float* s = ring[c & (RING - 1)];
#pragma unroll
        for (int j = 0; j < U; ++j) {
            ql[j] = fmaf(s[j * Cn + li],    128.0f, EPS128);
            qb[j] = fmaf(s[j * Cn + BLANK], 128.0f, EPS128);
        }
    };

    float E = 0.f, O = 0.f, X = 0.f;   // states 2i, 2i+1, 128(lane63)
    int Esum = 0;

    auto steps = [&](const float* ql, const float* qb, bool first) {
#pragma unroll
        for (int j = 0; j < U; ++j) {
            if (first && j == 0) {     // t=0: only states 0,1 reachable
                E = (i == 0) ? qb[0] : 0.f;
                O = (i == 0) ? ql[0] : 0.f;
                X = 0.f;
                continue;
            }
            const float Ol = dpp_movf<0x138>(O);   // state 2i-1 from left
            const float t1 = O + E;
            const float nO = fmaf(skf, Ol, t1) * ql[j];
            const float nE = (E + Ol) * qb[j];
            const float nX = (X + O) * qb[j];
            E = nE; O = nO; X = nX;
        }
    };
    auto renorm = [&]() {
        float m = fmaxf(E, O);
        if (i == 63) m = fmaxf(m, X);
        m = fmaxf(m, dpp_movf<0x111>(m));
        m = fmaxf(m, dpp_movf<0x112>(m));
        m = fmaxf(m, dpp_movf<0x114>(m));
        m = fmaxf(m, dpp_movf<0x118>(m));
        m = fmaxf(m, dpp_movf<0x142>(m));
        m = fmaxf(m, dpp_movf<0x143>(m));          // lane63 = wave max
        const unsigned ub =
            (unsigned)__builtin_amdgcn_readlane(__float_as_int(m), 63);
        const int eb = (int)(ub >> 23);
        const float sc = __int_as_float((unsigned)(254 - eb) << 23);
        Esum += eb - 127;
        E *= sc; O *= sc; X *= sc;
    };

    spinflag(0);
    qread(0, qlA, qbA);
    for (int c = 0; c < NCH - 2; c += 2) {
        spinflag(c + 1);
        qread(c + 1, qlB, qbB);
        steps(qlA, qbA, c == 0);
        renorm();
        if (i == 0) *vpr = c + 1;
        spinflag(c + 2);
        qread(c + 2, qlA, qbA);
        steps(qlB, qbB, false);
        renorm();
        if (i == 0) *vpr = c + 2;
    }
    spinflag(NCH - 1);
    qread(NCH - 1, qlB, qbB);
    steps(qlA, qbA, false);            // chunk 30
    renorm();
    if (i == 0) *vpr = NCH - 1;
    steps(qlB, qbB, false);            // chunk 31 (no renorm needed)

    if (i == 63) {
        const float s = O + X;         // alpha[127] + alpha[128] (scaled)
#if __has_builtin(__builtin_amdgcn_logf)
        const float l2 = __builtin_amdgcn_logf(s);
#else
        const float l2 = log2f(s);
#endif
        out[b] = -(l2 + (float)(Esum - 7 * Tn)) * LN2;
    }
}

extern "C" void kernel_launch(void* const* d_in, const int* in_sizes, int n_in,
                              void* d_out, int out_size, void* d_ws, size_t ws_size,
                              hipStream_t stream) {
    const int*   y_true = (const int*)d_in[0];
    const float* y_pred = (const float*)d_in[1];
    float*       out    = (float*)d_out;
    hipLaunchKernelGGL(ctc_pc_kernel, dim3(Bn), dim3(256), 0, stream,
                       y_true, y_pred, out);
}

// Round 8
// 205.486 us; speedup vs baseline: 1.0566x; 1.0566x over previous
//
#include <hip/hip_runtime.h>
#include <math.h>

// CTC forward (keras ctc_batch_cost), B=1024 T=256 C=128 L=64, S=129.
// R8: fused compact-then-scan. One 256-thread block per batch element,
// 42 KB LDS -> 3 blocks/CU.
//  Phase 1 (all 4 waves, throughput-shaped): per 8-row chunk, coalesced
//    float4 stage (depth-3 register prefetch) into LDS ping-pong; gather the
//    65 needed columns (64 labels + blank) from LDS and store a bf16 compact
//    tensor comp[32][8][65] (33 KB) that STAYS in LDS. One barrier per chunk
//    (ping-pong removes the second). No global scatter -> no TA address-
//    processing wall; no HBM round-trip; no spin flags.
//  Phase 2 (wave 0 only; waves 1-3 exit): validated probability-domain
//    recurrence (lane i owns states 2i/2i+1, state 128 on lane 63, one DPP
//    wave_shr:1 per step, renorm every 8 steps with exponent accumulator),
//    reading conflict-free bf16 LDS, zero barriers. Cross-block overlap
//    (3 blocks/CU) hides the serial tail behind other blocks' streaming.
// bf16 compaction error measured in R6: absmax 8.0 < threshold 21.76.

#define Bn 1024
#define Tn 256
#define Cn 128
#define Ln 64
#define BLANK 127
#define U 8
#define NCH (Tn / U)      // 32 chunks
#define ENT 65            // 64 label cols + blank
#define EPS128 (1e-7f * 128.0f)
#define LN2 0.69314718055994530942f

template <int CTRL>
__device__ __forceinline__ float dpp_movf(float x) {
    return __int_as_float(__builtin_amdgcn_update_dpp(
        0, __float_as_int(x), CTRL, 0xF, 0xF, true));
}
__device__ __forceinline__ int dpp_shr1_i(int x) {
    return __builtin_amdgcn_update_dpp(0, x, 0x138, 0xF, 0xF, true);
}
__device__ __forceinline__ unsigned short f2bf(float f) {   // RNE
    const unsigned u = __float_as_uint(f);
    return (unsigned short)((u + 0x7FFFu + ((u >> 16) & 1u)) >> 16);
}

__global__ __launch_bounds__(256)
void ctc_fused_kernel(const int* __restrict__ yt,
                      const float* __restrict__ yp,
                      float* __restrict__ out) {
    __shared__ unsigned short comp[NCH][U][ENT];        // 33280 B, bf16 q
    __shared__ __align__(16) float raw[2][U * Cn];      // 8 KB ping-pong
    __shared__ int lab[Ln];

    const int b = blockIdx.x;
    const int t = threadIdx.x;
    const int w = t >> 6;
    const int i = t & 63;

    if (t < Ln) lab[t] = yt[b * Ln + t];

    const float4* gsrc = (const float4*)(yp + (size_t)b * (Tn * Cn));

    // ---------------- phase 1: stage + gather + compact ----------------
    float4 vA = gsrc[t];
    float4 vB = gsrc[256 + t];
    float4 vC = gsrc[512 + t];
    const int j  = t >> 5;          // row within chunk, 0..7
    const int tb = t & 31;          // entry group, handles tb and tb+32

    for (int c = 0; c < NCH; ++c) {
        ((float4*)raw[c & 1])[t] = vA;
        vA = vB; vB = vC;
        if (c + 3 < NCH) vC = gsrc[(c + 3) * 256 + t];
        __syncthreads();            // stage visible (also covers lab on c=0)

        const float* rw = raw[c & 1] + j * Cn;
        const unsigned short q1 = f2bf(fmaf(rw[lab[tb]],      128.0f, EPS128));
        const unsigned short q2 = f2bf(fmaf(rw[lab[tb + 32]], 128.0f, EPS128));
        comp[c][j][tb]      = q1;
        comp[c][j][tb + 32] = q2;
        if (tb == 0)
            comp[c][j][64] = f2bf(fmaf(rw[BLANK], 128.0f, EPS128));
        // no second barrier: next store targets the other raw buffer, and the
        // barrier at c+1 (compiler emits lgkmcnt(0)) orders these LDS ops.
    }
    __syncthreads();                // comp complete

    if (w != 0) return;             // loader waves done

    // ---------------- phase 2: wave-0 serial recurrence ----------------
    const int li = lab[i];
    const int ll = dpp_shr1_i(li);
    const float skf = (li != ll) ? 1.0f : 0.0f;

    float qlA[U], qbA[U], qlB[U], qbB[U];
    auto qread = [&](int c, float* ql, float* qb) {
#pragma unroll
        for (int jj = 0; jj < U; ++jj) {
            ql[jj] = __uint_as_float((unsigned)comp[c][jj][i]  << 16);
            qb[jj] = __uint_as_float((unsigned)comp[c][jj][64] << 16);
        }
    };

    float E = 0.f, O = 0.f, X = 0.f;   // states 2i, 2i+1, 128(lane63)
    int Esum = 0;

    auto steps = [&](const float* ql, const float* qb, bool first) {
#pragma unroll
        for (int jj = 0; jj < U; ++jj) {
            if (first && jj == 0) {    // t=0: only states 0,1 reachable
                E = (i == 0) ? qb[0] : 0.f;
                O = (i == 0) ? ql[0] : 0.f;
                X = 0.f;
                continue;
            }
            const float Ol = dpp_movf<0x138>(O);   // state 2i-1 from left
            const float t1 = O + E;
            const float nO = fmaf(skf, Ol, t1) * ql[jj];
            const float nE = (E + Ol) * qb[jj];
            const float nX = (X + O) * qb[jj];
            E = nE; O = nO; X = nX;
        }
    };
    auto renorm = [&]() {
        float m = fmaxf(E, O);
        if (i == 63) m = fmaxf(m, X);
        m = fmaxf(m, dpp_movf<0x111>(m));
        m = fmaxf(m, dpp_movf<0x112>(m));
        m = fmaxf(m, dpp_movf<0x114>(m));
        m = fmaxf(m, dpp_movf<0x118>(m));
        m = fmaxf(m, dpp_movf<0x142>(m));
        m = fmaxf(m, dpp_movf<0x143>(m));          // lane63 = wave max
        const unsigned ub =
            (unsigned)__builtin_amdgcn_readlane(__float_as_int(m), 63);
        const int eb = (int)(ub >> 23);
        const float sc = __int_as_float((unsigned)(254 - eb) << 23);
        Esum += eb - 127;
        E *= sc; O *= sc; X *= sc;
    };

    qread(0, qlA, qbA);
    for (int c = 0; c < NCH - 2; c += 2) {
        qread(c + 1, qlB, qbB);
        steps(qlA, qbA, c == 0);
        renorm();
        qread(c + 2, qlA, qbA);
        steps(qlB, qbB, false);
        renorm();
    }
    qread(NCH - 1, qlB, qbB);
    steps(qlA, qbA, false);            // chunk 30
    renorm();
    steps(qlB, qbB, false);            // chunk 31 (no renorm before log)

    if (i == 63) {
        const float s = O + X;         // alpha[127] + alpha[128] (scaled)
#if __has_builtin(__builtin_amdgcn_logf)
        const float l2 = __builtin_amdgcn_logf(s);
#else
        const float l2 = log2f(s);
#endif
        out[b] = -(l2 + (float)(Esum - 7 * Tn)) * LN2;
    }
}

extern "C" void kernel_launch(void* const* d_in, const int* in_sizes, int n_in,
                              void* d_out, int out_size, void* d_ws, size_t ws_size,
                              hipStream_t stream) {
    const int*   y_true = (const int*)d_in[0];
    const float* y_pred = (const float*)d_in[1];
    float*       out    = (float*)d_out;
    hipLaunchKernelGGL(ctc_fused_kernel, dim3(Bn), dim3(256), 0, stream,
                       y_true, y_pred, out);
}

// Round 9
// 191.882 us; speedup vs baseline: 1.1316x; 1.0709x over previous
//
#include <hip/hip_runtime.h>
#include <math.h>

// CTC forward (keras ctc_batch_cost), B=1024 T=256 C=128 L=64, S=129.
// R9: all-register pipeline. One wave64 per batch element (1024 blocks x 64).
//  - y_pred streamed as coalesced float2 (lane i holds cols 2i,2i+1) into a
//    4-deep REGISTER ring: no LDS staging, no global_load_lds, no barriers,
//    no spin flags -> compiler emits precise per-register vmcnt waits (no
//    aliasing vmcnt(0) drains), and no per-lane scattered loads (no TA wall).
//  - label-column gather in-register: 2x ds_bpermute + cndmask per row
//    (full crossbar, fp32-exact); blank col 127 = readlane(r.y, 63).
//  - probability-domain semiring recurrence (validated R3-R8): lane i owns
//    states 2i / 2i+1, state 128 rides lane 63, one DPP wave_shr:1 per step.
//  - renorm every 16 steps (safe: q <= 128.6 => growth <= 2^112 < 2^127
//    from renormalized max in [1,2)); exponent accumulated in Esum.

#define Bn 1024
#define Tn 256
#define Cn 128
#define Ln 64
#define U 8
#define NCH (Tn / U)          // 32 chunks
#define EPS128 (1e-7f * 128.0f)
#define LN2 0.69314718055994530942f

template <int CTRL>
__device__ __forceinline__ float dpp_movf(float x) {
    return __int_as_float(__builtin_amdgcn_update_dpp(
        0, __float_as_int(x), CTRL, 0xF, 0xF, true));
}
__device__ __forceinline__ int dpp_shr1_i(int x) {
    return __builtin_amdgcn_update_dpp(0, x, 0x138, 0xF, 0xF, true);
}
__device__ __forceinline__ float bpermf(int baddr, float v) {
    return __int_as_float(__builtin_amdgcn_ds_bpermute(baddr, __float_as_int(v)));
}

__global__ __launch_bounds__(64)
void ctc_reg_kernel(const int* __restrict__ yt,
                    const float* __restrict__ yp,
                    float* __restrict__ out) {
    const int b = blockIdx.x;
    const int i = threadIdx.x;

    const int li = yt[b * Ln + i];
    const int ll = dpp_shr1_i(li);
    const float skf = (li != ll) ? 1.0f : 0.0f;
    const int  baddr = (li >> 1) << 2;     // bpermute source lane li>>1
    const bool sel   = (li & 1) != 0;

    const float2* gb = (const float2*)(yp + (size_t)b * (Tn * Cn));

    float2 R0[U], R1[U], R2[U], R3[U];
    float qlA[U], qbA[U], qlB[U], qbB[U];

    auto load = [&](int c, float2* r) {
        const float2* p = gb + (size_t)c * (U * Cn / 2) + i;
#pragma unroll
        for (int j = 0; j < U; ++j) r[j] = p[j * (Cn / 2)];   // 512B coalesced
    };
    auto conv = [&](const float2* r, float* ql, float* qb) {
#pragma unroll
        for (int j = 0; j < U; ++j) {
            const float gx = bpermf(baddr, r[j].x);           // even cols
            const float gy = bpermf(baddr, r[j].y);           // odd cols
            const float pv = sel ? gy : gx;
            ql[j] = fmaf(pv, 128.0f, EPS128);
            const float bk = __int_as_float(
                __builtin_amdgcn_readlane(__float_as_int(r[j].y), 63)); // col 127
            qb[j] = fmaf(bk, 128.0f, EPS128);
        }
    };

    float E = 0.f, O = 0.f, X = 0.f;       // states 2i, 2i+1, 128(lane63)
    int Esum = 0;

    auto steps = [&](const float* ql, const float* qb, bool first) {
#pragma unroll
        for (int j = 0; j < U; ++j) {
            if (first && j == 0) {         // t=0: only states 0,1 reachable
                E = (i == 0) ? qb[0] : 0.f;
                O = (i == 0) ? ql[0] : 0.f;
                X = 0.f;
                continue;
            }
            const float Ol = dpp_movf<0x138>(O);   // state 2i-1 (lane0 -> 0)
            const float t1 = O + E;
            const float nO = fmaf(skf, Ol, t1) * ql[j];
            const float nE = (E + Ol) * qb[j];
            const float nX = (X + O) * qb[j];
            E = nE; O = nO; X = nX;
        }
    };
    auto renorm = [&]() {                  // every 16 steps (2 chunks)
        float m = fmaxf(E, O);
        if (i == 63) m = fmaxf(m, X);
        m = fmaxf(m, dpp_movf<0x111>(m));
        m = fmaxf(m, dpp_movf<0x112>(m));
        m = fmaxf(m, dpp_movf<0x114>(m));
        m = fmaxf(m, dpp_movf<0x118>(m));
        m = fmaxf(m, dpp_movf<0x142>(m));
        m = fmaxf(m, dpp_movf<0x143>(m));  // lane63 = wave max
        const unsigned ub =
            (unsigned)__builtin_amdgcn_readlane(__float_as_int(m), 63);
        const int eb = (int)(ub >> 23);
        const float sc = __int_as_float((unsigned)(254 - eb) << 23);
        Esum += eb - 127;
        E *= sc; O *= sc; X *= sc;
    };

    // prologue: 4 chunks in flight, chunk 0 converted
    load(0, R0); load(1, R1); load(2, R2); load(3, R3);
    conv(R0, qlA, qbA);

    for (int cc = 0; cc < NCH; cc += 4) {
        // chunk cc (qA); convert cc+1; refill slot with cc+4
        conv(R1, qlB, qbB);
        if (cc + 4 < NCH) load(cc + 4, R0);
        steps(qlA, qbA, cc == 0);
        // chunk cc+1 (qB); convert cc+2
        conv(R2, qlA, qbA);
        if (cc + 5 < NCH) load(cc + 5, R1);
        steps(qlB, qbB, false);
        renorm();
        // chunk cc+2 (qA); convert cc+3
        conv(R3, qlB, qbB);
        if (cc + 6 < NCH) load(cc + 6, R2);
        steps(qlA, qbA, false);
        // chunk cc+3 (qB); convert cc+4 (lives in R0)
        if (cc + 4 < NCH) conv(R0, qlA, qbA);
        if (cc + 7 < NCH) load(cc + 7, R3);
        steps(qlB, qbB, false);
        renorm();
    }

    if (i == 63) {
        const float s = O + X;             // alpha[127] + alpha[128] (scaled)
#if __has_builtin(__builtin_amdgcn_logf)
        const float l2 = __builtin_amdgcn_logf(s);
#else
        const float l2 = log2f(s);
#endif
        out[b] = -(l2 + (float)(Esum - 7 * Tn)) * LN2;
    }
}

extern "C" void kernel_launch(void* const* d_in, const int* in_sizes, int n_in,
                              void* d_out, int out_size, void* d_ws, size_t ws_size,
                              hipStream_t stream) {
    const int*   y_true = (const int*)d_in[0];
    const float* y_pred = (const float*)d_in[1];
    float*       out    = (float*)d_out;
    hipLaunchKernelGGL(ctc_reg_kernel, dim3(Bn), dim3(64), 0, stream,
                       y_true, y_pred, out);
}